// Round 8
// baseline (405.848 us; speedup 1.0000x reference)
//
#include <hip/hip_runtime.h>
#include <hip/hip_fp16.h>
#include <cstdint>
#include <cstddef>

#define GLOBAL_AS __attribute__((address_space(1)))
#define LDS_AS    __attribute__((address_space(3)))

typedef __attribute__((ext_vector_type(8))) _Float16 f16x8;
typedef __attribute__((ext_vector_type(4))) float    f32x4;

__device__ __forceinline__ void gload_lds16(const void* g, void* l) {
    __builtin_amdgcn_global_load_lds((const GLOBAL_AS void*)g,
                                     (LDS_AS void*)l, 16, 0, 0);
}

// fp16 quantizer == reference fp_quantize_ste(exp=5, sig=10): RNE + saturate.
__device__ __forceinline__ __half qcvt(float x) {
    x = fminf(fmaxf(x, -65504.f), 65504.f);
    return __float2half(x);   // v_cvt_f16_f32: RNE, subnormals handled
}

// Fused quantization of x and w (both f32 -> f16), one launch, grid-stride.
__global__ void quant_xw_f32_to_f16(const float* __restrict__ xin, int x4,
                                    const float* __restrict__ win, int w4,
                                    __half* __restrict__ xout,
                                    __half* __restrict__ wout) {
    const int stride = gridDim.x * blockDim.x;
    const int tot = x4 + w4;
    for (int i = blockIdx.x * blockDim.x + threadIdx.x; i < tot; i += stride) {
        const bool isx = (i < x4);
        const int  j   = isx ? i : i - x4;
        const float4 f = reinterpret_cast<const float4*>(isx ? xin : win)[j];
        union { __half h[4]; uint2 u; } p;
        p.h[0] = qcvt(f.x);
        p.h[1] = qcvt(f.y);
        p.h[2] = qcvt(f.z);
        p.h[3] = qcvt(f.w);
        reinterpret_cast<uint2*>(isx ? xout : wout)[j] = p.u;
    }
}

// ---------------------------------------------------------------------------
// 256x256 tile, BK=64, 8 waves (2Mx4N), 4 phases/K-tile.
// ROUND 8: FULL one-phase-lookahead — no phase's MFMA waits on reads issued
// in that phase. Reads: P0->B1(t) [for P1], P1->A1(t) [for P2], P2->none,
// P3 (after vmcnt(6)+barrier confirming tile t+1) -> B0(t+1)+A0(t+1)
// [for t+1 P0, drained via 4-quarter counted lgkm split].
// Register budget: afX(A0) 32 + afY(A1) 32 + two B sets 16+16 = 96 VGPR.
// B sets rotate roles: within a tile, B1(t) and B0(t+1) time-share SV
// (B1 dies at P2, B0' lands at P3); SU/SV swap each tile (2-tile unroll).
//
// lgkm ledger/wave (DS in-order): P0 entry 12 (B0'4+afX8), +4 B1 = 16;
//   WAITL 10/8/6/4 retire B0'+af[m] quarter-by-quarter, leave 4 (B1).
// P1: +8 afY = 12; WAITL(8) retires B1. P2: WAITL(0) retires afY.
// P3: issue 12, MFMA(afY,SU) needs no wait.
// vmcnt: stages/tile = B0'(P0), A0''(P1), B1''(P2), A1''(P3) = 8 ops;
//   vmcnt(6) at P3 retires through B0(t+1) = all of tile t+1.
// WAR: every read retires at a WAITL before the phase-end barrier that
//   precedes the STAGE overwriting its region (checked per-region).
// ---------------------------------------------------------------------------
__global__ __launch_bounds__(512, 2) void gemm_f16_8phase(
    const __half* __restrict__ A, const __half* __restrict__ B,
    const float* __restrict__ bias, float* __restrict__ C,
    int M, int N, int K)
{
    __shared__ __align__(16) __half lds[2][2][2][8192];   // 128 KiB
    // layout: [buf](64KiB) [op A=0/B=1](32KiB) [half](16KiB) data

    const int tid  = threadIdx.x;
    const int lane = tid & 63;
    const int wid  = tid >> 6;     // 8 waves
    const int wr   = wid >> 2;     // 0..1 (M)
    const int wc   = wid & 3;      // 0..3 (N)
    const int fr   = lane & 15;
    const int fq   = lane >> 4;

    // bijective XCD swizzle (m204)
    const int nwg = gridDim.x;
    const int qq = nwg >> 3, rr = nwg & 7;
    const int xcd = blockIdx.x & 7, idx = blockIdx.x >> 3;
    const int wgid = (xcd < rr ? xcd * (qq + 1)
                               : rr * (qq + 1) + (xcd - rr) * qq) + idx;
    const int nbn = N >> 8;
    const int tile_m = (wgid / nbn) << 8;
    const int tile_n = (wgid % nbn) << 8;

    // ---- staging source coords (inverse of LDS swizzle, per thread) ----
    const int wbyte = (lane * 16) ^ (((lane >> 5) & 1) << 5);
    const int srow  = ((wid >> 1) << 4) + (wbyte >> 6);   // 0..63
    const int scb   = ((wid & 1) << 6) + (wbyte & 63);    // col byte 0..127
    const char* gA0 = (const char*)A + (size_t)(tile_m + srow) * K * 2 + scb;
    const char* gB0 = (const char*)B + (size_t)(tile_n + srow) * K * 2 + scb;
    const size_t rstep = (size_t)64  * K * 2;   // +64 rows
    const size_t hstep = (size_t)128 * K * 2;   // +1 half (128 rows)
    const int ldst = tid * 16;                  // linear LDS dest byte

    // ---- fragment-read LDS byte addresses (st_16x32 swizzled) ----
    const int woff = (fr * 64 + fq * 16) ^ (((fr >> 3) & 1) << 5);
    const uint32_t lds0 = (uint32_t)(size_t)(LDS_AS const char*)&lds[0][0][0][0];
    const uint32_t aBase = lds0 + (uint32_t)(wr * 8192 + woff);
    const uint32_t bBase = lds0 + 32768u + (uint32_t)(wc * 4096 + woff);

    f32x4 acc[2][2][4][2];
#pragma unroll
    for (int qa = 0; qa < 2; ++qa)
#pragma unroll
        for (int qb = 0; qb < 2; ++qb)
#pragma unroll
            for (int m = 0; m < 4; ++m)
#pragma unroll
                for (int n = 0; n < 2; ++n)
                    acc[qa][qb][m][n] = (f32x4){0.f, 0.f, 0.f, 0.f};

    f16x8 afX[4][2];   // A half-0 fragments (A0 of current tile)
    f16x8 afY[4][2];   // A half-1 fragments (A1 of current tile)
    f16x8 bfU[2][2];   // B set U
    f16x8 bfV[2][2];   // B set V

#define STAGE_A(bufi, h, kt) do {                                          \
        char* l_ = (char*)(&lds[bufi][0][h][0]) + ldst;                    \
        const char* g_ = gA0 + (size_t)(kt) * 128 + ((h) ? hstep : 0);     \
        gload_lds16(g_, l_);                                               \
        gload_lds16(g_ + rstep, l_ + 8192);                                \
    } while (0)

#define STAGE_B(bufi, h, kt) do {                                          \
        char* l_ = (char*)(&lds[bufi][1][h][0]) + ldst;                    \
        const char* g_ = gB0 + (size_t)(kt) * 128 + ((h) ? hstep : 0);     \
        gload_lds16(g_, l_);                                               \
        gload_lds16(g_ + rstep, l_ + 8192);                                \
    } while (0)

// inline-asm ds_read_b128 (volatile: program order among volatiles kept)
#define DSR(dst, addr, OFF)                                                \
    asm volatile("ds_read_b128 %0, %1 offset:" OFF                         \
                 : "=v"(dst) : "v"(addr))

#define LDGA(dst, bufi, qa) do {                                           \
        const uint32_t a_ = aBase + (bufi) * 65536u + (qa) * 16384u;       \
        DSR(dst[0][0], a_, "0");    DSR(dst[0][1], a_, "1024");            \
        DSR(dst[1][0], a_, "2048"); DSR(dst[1][1], a_, "3072");            \
        DSR(dst[2][0], a_, "4096"); DSR(dst[2][1], a_, "5120");            \
        DSR(dst[3][0], a_, "6144"); DSR(dst[3][1], a_, "7168");            \
    } while (0)

#define LDGB(dst, bufi, hb) do {                                           \
        const uint32_t b_ = bBase + (bufi) * 65536u + (hb) * 16384u;       \
        DSR(dst[0][0], b_, "0");    DSR(dst[0][1], b_, "1024");            \
        DSR(dst[1][0], b_, "2048"); DSR(dst[1][1], b_, "3072");            \
    } while (0)

#define MMA_PAIR(qa, qb, mm, nn, AF, BF)                                   \
    acc[qa][qb][mm][nn] = __builtin_amdgcn_mfma_f32_16x16x32_f16(          \
        AF[mm][0], BF[nn][0], acc[qa][qb][mm][nn], 0, 0, 0);               \
    acc[qa][qb][mm][nn] = __builtin_amdgcn_mfma_f32_16x16x32_f16(          \
        AF[mm][1], BF[nn][1], acc[qa][qb][mm][nn], 0, 0, 0);

// one m-row quarter (4 MFMAs)
#define MMA_Q(qa, qb, mm, AF, BF)                                          \
    __builtin_amdgcn_s_setprio(1);                                         \
    MMA_PAIR(qa, qb, mm, 0, AF, BF) MMA_PAIR(qa, qb, mm, 1, AF, BF)        \
    __builtin_amdgcn_s_setprio(0);

#define MMA_FULL(qa, qb, AF, BF)                                           \
    __builtin_amdgcn_s_setprio(1);                                         \
    MMA_PAIR(qa, qb, 0, 0, AF, BF) MMA_PAIR(qa, qb, 0, 1, AF, BF)          \
    MMA_PAIR(qa, qb, 1, 0, AF, BF) MMA_PAIR(qa, qb, 1, 1, AF, BF)          \
    MMA_PAIR(qa, qb, 2, 0, AF, BF) MMA_PAIR(qa, qb, 2, 1, AF, BF)          \
    MMA_PAIR(qa, qb, 3, 0, AF, BF) MMA_PAIR(qa, qb, 3, 1, AF, BF)          \
    __builtin_amdgcn_s_setprio(0);

// counted lgkm wait + scheduler fence (rule #18)
#define WAITL(NLIT)                                                        \
    asm volatile("s_waitcnt lgkmcnt(" NLIT ")");                           \
    __builtin_amdgcn_sched_barrier(0)

#define BARS()                                                             \
    __builtin_amdgcn_s_barrier();                                          \
    __builtin_amdgcn_sched_barrier(0)

// P0 body: entry lgkm=12 (B0'4 + afX8, oldest-first B0'); +4 B1 reads = 16.
#define PHASE0(SU, SV, STMT)                                               \
    STMT;                                                                  \
    LDGB(SV, 99, 99); /* placeholder never used */                         \
    BARS()
// (placeholder removed below — real phases written inline for clarity)

#define TILE_FULL(cur, nxt, kt, SU, SV)                                    \
    /* P0: MFMA(A0,B0=SU); issue B1(t)->SV; stage B0(t+1)->nxt */          \
    STAGE_B(nxt, 0, (kt) + 1);                                             \
    LDGB(SV, cur, 1);                                                      \
    WAITL("10"); MMA_Q(0, 0, 0, afX, SU);                                  \
    WAITL("8");  MMA_Q(0, 0, 1, afX, SU);                                  \
    WAITL("6");  MMA_Q(0, 0, 2, afX, SU);                                  \
    WAITL("4");  MMA_Q(0, 0, 3, afX, SU);                                  \
    BARS();                                                                \
    /* P1: MFMA(A0,B1=SV); issue A1(t)->afY; stage A0(t+2)->cur */         \
    STAGE_A(cur, 0, (kt) + 2);                                             \
    LDGA(afY, cur, 1);                                                     \
    WAITL("8"); MMA_FULL(0, 1, afX, SV);                                   \
    BARS();                                                                \
    /* P2: MFMA(A1,B1); stage B1(t+2)->cur */                              \
    STAGE_B(cur, 1, (kt) + 2);                                             \
    WAITL("0"); MMA_FULL(1, 1, afY, SV);                                   \
    BARS();                                                                \
    /* P3: stage A1(t+2); confirm tile t+1; issue B0'+A0'; MFMA(A1,B0) */  \
    STAGE_A(cur, 1, (kt) + 2);                                             \
    asm volatile("s_waitcnt vmcnt(6)");                                    \
    BARS();                                                                \
    LDGB(SV, nxt, 0);                                                      \
    LDGA(afX, nxt, 0);                                                     \
    __builtin_amdgcn_sched_barrier(0);                                     \
    MMA_FULL(1, 0, afY, SU);                                               \
    BARS();

    // ---- prologue: stage tile0 fully + tile1 (A0,B1,A1); B0(1) in-loop ----
    STAGE_A(0, 0, 0); STAGE_B(0, 0, 0); STAGE_B(0, 1, 0); STAGE_A(0, 1, 0);
    STAGE_A(1, 0, 1); STAGE_B(1, 1, 1); STAGE_A(1, 1, 1);
    asm volatile("s_waitcnt vmcnt(6)");   // tile0 fully arrived
    BARS();
    LDGB(bfU, 0, 0);                      // B0(0) -> U  (oldest 4)
    LDGA(afX, 0, 0);                      // A0(0) -> afX (next 8)
    __builtin_amdgcn_sched_barrier(0);

    const int nt = K >> 6;              // even, >= 4 (guarded by launcher)
    for (int kt = 0; kt + 3 < nt; kt += 2) {
        TILE_FULL(0, 1, kt,     bfU, bfV);
        TILE_FULL(1, 0, kt + 1, bfV, bfU);
    }

    // ---- tile nt-2 (buf0, SU=U, SV=V): stage only B0(nt-1) ----
    STAGE_B(1, 0, nt - 1);
    LDGB(bfV, 0, 1);
    WAITL("10"); MMA_Q(0, 0, 0, afX, bfU);
    WAITL("8");  MMA_Q(0, 0, 1, afX, bfU);
    WAITL("6");  MMA_Q(0, 0, 2, afX, bfU);
    WAITL("4");  MMA_Q(0, 0, 3, afX, bfU);
    BARS();
    LDGA(afY, 0, 1);
    WAITL("8"); MMA_FULL(0, 1, afX, bfV);
    BARS();
    WAITL("0"); MMA_FULL(1, 1, afY, bfV);
    BARS();
    asm volatile("s_waitcnt vmcnt(0)");
    BARS();
    LDGB(bfV, 1, 0);
    LDGA(afX, 1, 0);
    __builtin_amdgcn_sched_barrier(0);
    MMA_FULL(1, 0, afY, bfU);
    BARS();

    // ---- tile nt-1 (buf1, SU=V, SV=U): pure compute ----
    LDGB(bfU, 1, 1);
    WAITL("10"); MMA_Q(0, 0, 0, afX, bfV);
    WAITL("8");  MMA_Q(0, 0, 1, afX, bfV);
    WAITL("6");  MMA_Q(0, 0, 2, afX, bfV);
    WAITL("4");  MMA_Q(0, 0, 3, afX, bfV);
    BARS();
    LDGA(afY, 1, 1);
    WAITL("8"); MMA_FULL(0, 1, afX, bfU);
    BARS();
    WAITL("0"); MMA_FULL(1, 1, afY, bfU);
    BARS();
    MMA_FULL(1, 0, afY, bfV);

    // ---- epilogue: C/D layout col=lane&15, row=fq*4+reg (m89-verified) ----
    float bv[2][2];
#pragma unroll
    for (int qb = 0; qb < 2; ++qb)
#pragma unroll
        for (int n = 0; n < 2; ++n)
            bv[qb][n] = __half2float(qcvt(
                bias[tile_n + qb * 128 + wc * 32 + n * 16 + fr]));

#pragma unroll
    for (int qa = 0; qa < 2; ++qa)
#pragma unroll
        for (int qb = 0; qb < 2; ++qb)
#pragma unroll
            for (int m = 0; m < 4; ++m)
#pragma unroll
                for (int n = 0; n < 2; ++n) {
                    const int col = tile_n + qb * 128 + wc * 32 + n * 16 + fr;
                    const int rowb = tile_m + qa * 128 + wr * 64 + m * 16 + fq * 4;
#pragma unroll
                    for (int r = 0; r < 4; ++r)
                        C[(size_t)(rowb + r) * N + col] =
                            acc[qa][qb][m][n][r] + bv[qb][n];
                }

#undef STAGE_A
#undef STAGE_B
#undef DSR
#undef LDGA
#undef LDGB
#undef MMA_PAIR
#undef MMA_Q
#undef MMA_FULL
#undef WAITL
#undef BARS
#undef TILE_FULL
#undef PHASE0
}

// ---------------------------------------------------------------------------
// Insurance fallback (shape or ws mismatch): fused naive, slow but correct.
// ---------------------------------------------------------------------------
__global__ void qat_gemm_naive(const float* __restrict__ A,
                               const float* __restrict__ B,
                               const float* __restrict__ bias,
                               float* __restrict__ C, int M, int N, int K) {
    const int col = blockIdx.x * blockDim.x + threadIdx.x;
    const int row = blockIdx.y;
    if (col >= N || row >= M) return;
    float s = 0.f;
    for (int k = 0; k < K; ++k) {
        float a = __half2float(qcvt(A[(size_t)row * K + k]));
        float b = __half2float(qcvt(B[(size_t)col * K + k]));
        s += a * b;
    }
    C[(size_t)row * N + col] = s + __half2float(qcvt(bias[col]));
}

// ---------------------------------------------------------------------------
extern "C" void kernel_launch(void* const* d_in, const int* in_sizes, int n_in,
                              void* d_out, int out_size, void* d_ws,
                              size_t ws_size, hipStream_t stream) {
    const float* x = (const float*)d_in[0];
    const float* w = (const float*)d_in[1];
    const float* b = (const float*)d_in[2];
    float* out = (float*)d_out;

    const int xn = in_sizes[0];     // M*K
    const int wn = in_sizes[1];     // N*K
    const int N  = in_sizes[2];     // 4096
    const int K  = wn / N;          // 4096
    const int M  = xn / K;          // 8192

    const size_t need = (size_t)(xn + wn) * sizeof(__half);
    const bool ok = (M % 256 == 0) && (N % 256 == 0) &&
                    (K % 128 == 0) && (K >= 256);

    if (ws_size >= need && ok) {
        __half* xq = (__half*)d_ws;
        __half* wq = xq + xn;

        const int x4 = xn / 4, w4 = wn / 4;
        int blk = ((x4 + w4) + 255) / 256; if (blk > 2048) blk = 2048;
        quant_xw_f32_to_f16<<<blk, 256, 0, stream>>>(x, x4, w, w4, xq, wq);

        dim3 grid((M / 256) * (N / 256));
        gemm_f16_8phase<<<grid, 512, 0, stream>>>(xq, wq, b, out, M, N, K);
    } else {
        dim3 grid((N + 255) / 256, M);
        qat_gemm_naive<<<grid, 256, 0, stream>>>(x, w, b, out, M, N, K);
    }
}

// Round 9
// 282.276 us; speedup vs baseline: 1.4378x; 1.4378x over previous
//
#include <hip/hip_runtime.h>
#include <hip/hip_fp16.h>
#include <cstdint>
#include <cstddef>

#define GLOBAL_AS __attribute__((address_space(1)))
#define LDS_AS    __attribute__((address_space(3)))

typedef __attribute__((ext_vector_type(8))) _Float16 f16x8;
typedef __attribute__((ext_vector_type(4))) float    f32x4;

__device__ __forceinline__ void gload_lds16(const void* g, void* l) {
    __builtin_amdgcn_global_load_lds((const GLOBAL_AS void*)g,
                                     (LDS_AS void*)l, 16, 0, 0);
}

// fp16 quantizer == reference fp_quantize_ste(exp=5, sig=10): RNE + saturate.
__device__ __forceinline__ __half qcvt(float x) {
    x = fminf(fmaxf(x, -65504.f), 65504.f);
    return __float2half(x);   // v_cvt_f16_f32: RNE, subnormals handled
}

// Fused quantization of x and w (both f32 -> f16), one launch, grid-stride.
__global__ void quant_xw_f32_to_f16(const float* __restrict__ xin, int x4,
                                    const float* __restrict__ win, int w4,
                                    __half* __restrict__ xout,
                                    __half* __restrict__ wout) {
    const int stride = gridDim.x * blockDim.x;
    const int tot = x4 + w4;
    for (int i = blockIdx.x * blockDim.x + threadIdx.x; i < tot; i += stride) {
        const bool isx = (i < x4);
        const int  j   = isx ? i : i - x4;
        const float4 f = reinterpret_cast<const float4*>(isx ? xin : win)[j];
        union { __half h[4]; uint2 u; } p;
        p.h[0] = qcvt(f.x);
        p.h[1] = qcvt(f.y);
        p.h[2] = qcvt(f.z);
        p.h[3] = qcvt(f.w);
        reinterpret_cast<uint2*>(isx ? xout : wout)[j] = p.u;
    }
}

// ---------------------------------------------------------------------------
// 256x256 tile, BK=64, 8 waves (2Mx4N), 4 phases/K-tile.
// ROUND 9: R7 schedule + INTRA-PHASE software pipeline. Each A-phase
// interleaves read-issue and MFMA at quarter (2-read / 4-MFMA) granularity
// with counted lgkm waits, so the DS drain hides under the matrix pipe
// instead of preceding it. Register-neutral (lookahead stays inside af).
//
// Phases: P0=(A0,B0) P1=(A0,B1) P2=(A1,B1) P3=(A1,B0)
// Reads: P0 af<-A0 (8, interleaved); P1 B1 (4, interleaved); P2 af<-A1 (8,
//   interleaved); P3 (after vmcnt(6)+barrier) next-tile B0 (4, no wait).
// Staging: P0: B0(t+1)->nxt  P1: A0(t+2)->cur  P2: B1(t+2)->cur
//          P3: A1(t+2)->cur, then vmcnt(6) == tile t+1 fully arrived.
// lgkm ledgers (DS in-order/wave): P0 entry 4 (B0'); +q0+q1=8; W2 retires
//   B0'+q0; +q2 W2 retires q1; +q3 W2 retires q2; W0. P1: +4; W2; W0.
//   P2: +q0+q1=4; W2; +q2 W2; +q3 W2; W0. P3: issue 4, no wait.
// Every phase ends at lgkm 0 (except P3's 4 carried) -> WAR vs next-phase
// STAGE protected by the inter-phase barrier (as in R7, proven).
// ---------------------------------------------------------------------------
__global__ __launch_bounds__(512, 2) void gemm_f16_8phase(
    const __half* __restrict__ A, const __half* __restrict__ B,
    const float* __restrict__ bias, float* __restrict__ C,
    int M, int N, int K)
{
    __shared__ __align__(16) __half lds[2][2][2][8192];   // 128 KiB
    // layout: [buf](64KiB) [op A=0/B=1](32KiB) [half](16KiB) data

    const int tid  = threadIdx.x;
    const int lane = tid & 63;
    const int wid  = tid >> 6;     // 8 waves
    const int wr   = wid >> 2;     // 0..1 (M)
    const int wc   = wid & 3;      // 0..3 (N)
    const int fr   = lane & 15;
    const int fq   = lane >> 4;

    // bijective XCD swizzle (m204)
    const int nwg = gridDim.x;
    const int qq = nwg >> 3, rr = nwg & 7;
    const int xcd = blockIdx.x & 7, idx = blockIdx.x >> 3;
    const int wgid = (xcd < rr ? xcd * (qq + 1)
                               : rr * (qq + 1) + (xcd - rr) * qq) + idx;
    const int nbn = N >> 8;
    const int tile_m = (wgid / nbn) << 8;
    const int tile_n = (wgid % nbn) << 8;

    // ---- staging source coords (inverse of LDS swizzle, per thread) ----
    const int wbyte = (lane * 16) ^ (((lane >> 5) & 1) << 5);
    const int srow  = ((wid >> 1) << 4) + (wbyte >> 6);   // 0..63
    const int scb   = ((wid & 1) << 6) + (wbyte & 63);    // col byte 0..127
    const char* gA0 = (const char*)A + (size_t)(tile_m + srow) * K * 2 + scb;
    const char* gB0 = (const char*)B + (size_t)(tile_n + srow) * K * 2 + scb;
    const size_t rstep = (size_t)64  * K * 2;   // +64 rows
    const size_t hstep = (size_t)128 * K * 2;   // +1 half (128 rows)
    const int ldst = tid * 16;                  // linear LDS dest byte

    // ---- fragment-read LDS byte addresses (st_16x32 swizzled) ----
    const int woff = (fr * 64 + fq * 16) ^ (((fr >> 3) & 1) << 5);
    const uint32_t lds0 = (uint32_t)(size_t)(LDS_AS const char*)&lds[0][0][0][0];
    const uint32_t aBase = lds0 + (uint32_t)(wr * 8192 + woff);
    const uint32_t bBase = lds0 + 32768u + (uint32_t)(wc * 4096 + woff);

    f32x4 acc[2][2][4][2];
#pragma unroll
    for (int qa = 0; qa < 2; ++qa)
#pragma unroll
        for (int qb = 0; qb < 2; ++qb)
#pragma unroll
            for (int m = 0; m < 4; ++m)
#pragma unroll
                for (int n = 0; n < 2; ++n)
                    acc[qa][qb][m][n] = (f32x4){0.f, 0.f, 0.f, 0.f};

    f16x8 af[4][2];    // A fragments of the current half
    f16x8 bfP[2][2];   // B set ping
    f16x8 bfQ[2][2];   // B set pong

#define STAGE_A(bufi, h, kt) do {                                          \
        char* l_ = (char*)(&lds[bufi][0][h][0]) + ldst;                    \
        const char* g_ = gA0 + (size_t)(kt) * 128 + ((h) ? hstep : 0);     \
        gload_lds16(g_, l_);                                               \
        gload_lds16(g_ + rstep, l_ + 8192);                                \
    } while (0)

#define STAGE_B(bufi, h, kt) do {                                          \
        char* l_ = (char*)(&lds[bufi][1][h][0]) + ldst;                    \
        const char* g_ = gB0 + (size_t)(kt) * 128 + ((h) ? hstep : 0);     \
        gload_lds16(g_, l_);                                               \
        gload_lds16(g_ + rstep, l_ + 8192);                                \
    } while (0)

// inline-asm ds_read_b128 (volatile: program order among volatiles kept)
#define DSR(dst, addr, OFF)                                                \
    asm volatile("ds_read_b128 %0, %1 offset:" OFF                         \
                 : "=v"(dst) : "v"(addr))

// one A quarter: 2 reads (af[mm][0], af[mm][1])
#define LDGA_Q(bufi, qa, mm) do {                                          \
        const uint32_t a_ = aBase + (bufi) * 65536u + (qa) * 16384u        \
                            + (mm) * 2048u;                                \
        DSR(af[mm][0], a_, "0"); DSR(af[mm][1], a_, "1024");               \
    } while (0)

// one B half: 2 reads (dst[nn][0], dst[nn][1])
#define LDGB_Q(dst, bufi, hb, nn) do {                                     \
        const uint32_t b_ = bBase + (bufi) * 65536u + (hb) * 16384u        \
                            + (nn) * 2048u;                                \
        DSR(dst[nn][0], b_, "0"); DSR(dst[nn][1], b_, "1024");             \
    } while (0)

#define MMA_PAIR(qa, qb, mm, nn, BF)                                       \
    acc[qa][qb][mm][nn] = __builtin_amdgcn_mfma_f32_16x16x32_f16(          \
        af[mm][0], BF[nn][0], acc[qa][qb][mm][nn], 0, 0, 0);               \
    acc[qa][qb][mm][nn] = __builtin_amdgcn_mfma_f32_16x16x32_f16(          \
        af[mm][1], BF[nn][1], acc[qa][qb][mm][nn], 0, 0, 0);

// 4 MFMA: one m-row (both nn)
#define MMA_Q4(qa, qb, mm, BF)                                             \
    __builtin_amdgcn_s_setprio(1);                                         \
    MMA_PAIR(qa, qb, mm, 0, BF) MMA_PAIR(qa, qb, mm, 1, BF)                \
    __builtin_amdgcn_s_setprio(0);

// 8 MFMA: one nn column (all m)
#define MMA_N8(qa, qb, nn, BF)                                             \
    __builtin_amdgcn_s_setprio(1);                                         \
    MMA_PAIR(qa, qb, 0, nn, BF) MMA_PAIR(qa, qb, 1, nn, BF)                \
    MMA_PAIR(qa, qb, 2, nn, BF) MMA_PAIR(qa, qb, 3, nn, BF)                \
    __builtin_amdgcn_s_setprio(0);

// 16 MFMA
#define MMA_F16(qa, qb, BF)                                                \
    __builtin_amdgcn_s_setprio(1);                                         \
    MMA_PAIR(qa, qb, 0, 0, BF) MMA_PAIR(qa, qb, 0, 1, BF)                  \
    MMA_PAIR(qa, qb, 1, 0, BF) MMA_PAIR(qa, qb, 1, 1, BF)                  \
    MMA_PAIR(qa, qb, 2, 0, BF) MMA_PAIR(qa, qb, 2, 1, BF)                  \
    MMA_PAIR(qa, qb, 3, 0, BF) MMA_PAIR(qa, qb, 3, 1, BF)                  \
    __builtin_amdgcn_s_setprio(0);

// counted lgkm wait + scheduler fence (rule #18)
#define WAITL(NLIT)                                                        \
    asm volatile("s_waitcnt lgkmcnt(" NLIT ")");                           \
    __builtin_amdgcn_sched_barrier(0)

#define BARS()                                                             \
    __builtin_amdgcn_s_barrier();                                          \
    __builtin_amdgcn_sched_barrier(0)

// A-phase with intra-phase pipeline (8 reads, 16 MFMA)
#define PHASE_A(bufi, qa, pqa, pqb, BF)                                    \
    LDGA_Q(bufi, qa, 0); LDGA_Q(bufi, qa, 1);                              \
    WAITL("2"); MMA_Q4(pqa, pqb, 0, BF);                                   \
    LDGA_Q(bufi, qa, 2);                                                   \
    WAITL("2"); MMA_Q4(pqa, pqb, 1, BF);                                   \
    LDGA_Q(bufi, qa, 3);                                                   \
    WAITL("2"); MMA_Q4(pqa, pqb, 2, BF);                                   \
    WAITL("0"); MMA_Q4(pqa, pqb, 3, BF)

// B-phase with intra-phase pipeline (4 reads, 16 MFMA)
#define PHASE_B(dst, bufi, hb, pqa, pqb)                                   \
    LDGB_Q(dst, bufi, hb, 0); LDGB_Q(dst, bufi, hb, 1);                    \
    WAITL("2"); MMA_N8(pqa, pqb, 0, dst);                                  \
    WAITL("0"); MMA_N8(pqa, pqb, 1, dst)

#define TILE_FULL(cur, nxt, kt, SU, SV)                                    \
    /* P0: MFMA(A0,B0=SU) ; af<-A0 interleaved ; stage B0(t+1)->nxt */     \
    LDGA_Q(cur, 0, 0); LDGA_Q(cur, 0, 1); STAGE_B(nxt, 0, (kt) + 1);       \
    WAITL("2"); MMA_Q4(0, 0, 0, SU);                                       \
    LDGA_Q(cur, 0, 2);                                                     \
    WAITL("2"); MMA_Q4(0, 0, 1, SU);                                       \
    LDGA_Q(cur, 0, 3);                                                     \
    WAITL("2"); MMA_Q4(0, 0, 2, SU);                                       \
    WAITL("0"); MMA_Q4(0, 0, 3, SU);                                       \
    BARS();                                                                \
    /* P1: MFMA(A0,B1=SV) ; B1 interleaved ; stage A0(t+2)->cur */         \
    LDGB_Q(SV, cur, 1, 0); LDGB_Q(SV, cur, 1, 1); STAGE_A(cur, 0, (kt)+2); \
    WAITL("2"); MMA_N8(0, 1, 0, SV);                                       \
    WAITL("0"); MMA_N8(0, 1, 1, SV);                                       \
    BARS();                                                                \
    /* P2: MFMA(A1,B1=SV) ; af<-A1 interleaved ; stage B1(t+2)->cur */     \
    LDGA_Q(cur, 1, 0); LDGA_Q(cur, 1, 1); STAGE_B(cur, 1, (kt) + 2);       \
    WAITL("2"); MMA_Q4(1, 1, 0, SV);                                       \
    LDGA_Q(cur, 1, 2);                                                     \
    WAITL("2"); MMA_Q4(1, 1, 1, SV);                                       \
    LDGA_Q(cur, 1, 3);                                                     \
    WAITL("2"); MMA_Q4(1, 1, 2, SV);                                       \
    WAITL("0"); MMA_Q4(1, 1, 3, SV);                                       \
    BARS();                                                                \
    /* P3: stage A1(t+2); confirm t+1; pre-read B0(t+1)->SV; MFMA(A1,B0) */\
    STAGE_A(cur, 1, (kt) + 2);                                             \
    asm volatile("s_waitcnt vmcnt(6)");                                    \
    BARS();                                                                \
    LDGB_Q(SV, nxt, 0, 0); LDGB_Q(SV, nxt, 0, 1);                          \
    __builtin_amdgcn_sched_barrier(0);                                     \
    MMA_F16(1, 0, SU);                                                     \
    BARS();

    // ---- prologue: stage tile0 fully + tile1 (A0,B1,A1); B0(1) in-loop ----
    STAGE_A(0, 0, 0); STAGE_B(0, 0, 0); STAGE_B(0, 1, 0); STAGE_A(0, 1, 0);
    STAGE_A(1, 0, 1); STAGE_B(1, 1, 1); STAGE_A(1, 1, 1);
    asm volatile("s_waitcnt vmcnt(6)");   // tile0 fully arrived
    BARS();
    LDGB_Q(bfP, 0, 0, 0); LDGB_Q(bfP, 0, 0, 1);   // B0(0) -> P (4 carried)
    __builtin_amdgcn_sched_barrier(0);

    const int nt = K >> 6;              // even, >= 4 (guarded by launcher)
    for (int kt = 0; kt + 3 < nt; kt += 2) {
        TILE_FULL(0, 1, kt,     bfP, bfQ);
        TILE_FULL(1, 0, kt + 1, bfQ, bfP);
    }

    // ---- tile nt-2 (buf0, SU=P, SV=Q): stage only B0(nt-1) ----
    LDGA_Q(0, 0, 0); LDGA_Q(0, 0, 1); STAGE_B(1, 0, nt - 1);
    WAITL("2"); MMA_Q4(0, 0, 0, bfP);
    LDGA_Q(0, 0, 2);
    WAITL("2"); MMA_Q4(0, 0, 1, bfP);
    LDGA_Q(0, 0, 3);
    WAITL("2"); MMA_Q4(0, 0, 2, bfP);
    WAITL("0"); MMA_Q4(0, 0, 3, bfP);
    BARS();
    PHASE_B(bfQ, 0, 1, 0, 1);
    BARS();
    PHASE_A(0, 1, 1, 1, bfQ);
    BARS();
    asm volatile("s_waitcnt vmcnt(0)");
    BARS();
    LDGB_Q(bfQ, 1, 0, 0); LDGB_Q(bfQ, 1, 0, 1);   // B0(nt-1) -> Q
    __builtin_amdgcn_sched_barrier(0);
    MMA_F16(1, 0, bfP);
    BARS();

    // ---- tile nt-1 (buf1, SU=Q, SV=P): pure compute ----
    PHASE_A(1, 0, 0, 0, bfQ);
    BARS();
    PHASE_B(bfP, 1, 1, 0, 1);
    BARS();
    PHASE_A(1, 1, 1, 1, bfP);
    BARS();
    MMA_F16(1, 0, bfQ);

    // ---- epilogue: C/D layout col=lane&15, row=fq*4+reg (m89-verified) ----
    float bv[2][2];
#pragma unroll
    for (int qb = 0; qb < 2; ++qb)
#pragma unroll
        for (int n = 0; n < 2; ++n)
            bv[qb][n] = __half2float(qcvt(
                bias[tile_n + qb * 128 + wc * 32 + n * 16 + fr]));

#pragma unroll
    for (int qa = 0; qa < 2; ++qa)
#pragma unroll
        for (int qb = 0; qb < 2; ++qb)
#pragma unroll
            for (int m = 0; m < 4; ++m)
#pragma unroll
                for (int n = 0; n < 2; ++n) {
                    const int col = tile_n + qb * 128 + wc * 32 + n * 16 + fr;
                    const int rowb = tile_m + qa * 128 + wr * 64 + m * 16 + fq * 4;
#pragma unroll
                    for (int r = 0; r < 4; ++r)
                        C[(size_t)(rowb + r) * N + col] =
                            acc[qa][qb][m][n][r] + bv[qb][n];
                }

#undef STAGE_A
#undef STAGE_B
#undef DSR
#undef LDGA_Q
#undef LDGB_Q
#undef MMA_PAIR
#undef MMA_Q4
#undef MMA_N8
#undef MMA_F16
#undef WAITL
#undef BARS
#undef PHASE_A
#undef PHASE_B
#undef TILE_FULL
}

// ---------------------------------------------------------------------------
// Insurance fallback (shape or ws mismatch): fused naive, slow but correct.
// ---------------------------------------------------------------------------
__global__ void qat_gemm_naive(const float* __restrict__ A,
                               const float* __restrict__ B,
                               const float* __restrict__ bias,
                               float* __restrict__ C, int M, int N, int K) {
    const int col = blockIdx.x * blockDim.x + threadIdx.x;
    const int row = blockIdx.y;
    if (col >= N || row >= M) return;
    float s = 0.f;
    for (int k = 0; k < K; ++k) {
        float a = __half2float(qcvt(A[(size_t)row * K + k]));
        float b = __half2float(qcvt(B[(size_t)col * K + k]));
        s += a * b;
    }
    C[(size_t)row * N + col] = s + __half2float(qcvt(bias[col]));
}

// ---------------------------------------------------------------------------
extern "C" void kernel_launch(void* const* d_in, const int* in_sizes, int n_in,
                              void* d_out, int out_size, void* d_ws,
                              size_t ws_size, hipStream_t stream) {
    const float* x = (const float*)d_in[0];
    const float* w = (const float*)d_in[1];
    const float* b = (const float*)d_in[2];
    float* out = (float*)d_out;

    const int xn = in_sizes[0];     // M*K
    const int wn = in_sizes[1];     // N*K
    const int N  = in_sizes[2];     // 4096
    const int K  = wn / N;          // 4096
    const int M  = xn / K;          // 8192

    const size_t need = (size_t)(xn + wn) * sizeof(__half);
    const bool ok = (M % 256 == 0) && (N % 256 == 0) &&
                    (K % 128 == 0) && (K >= 256);

    if (ws_size >= need && ok) {
        __half* xq = (__half*)d_ws;
        __half* wq = xq + xn;

        const int x4 = xn / 4, w4 = wn / 4;
        int blk = ((x4 + w4) + 255) / 256; if (blk > 2048) blk = 2048;
        quant_xw_f32_to_f16<<<blk, 256, 0, stream>>>(x, x4, w, w4, xq, wq);

        dim3 grid((M / 256) * (N / 256));
        gemm_f16_8phase<<<grid, 512, 0, stream>>>(xq, wq, b, out, M, N, K);
    } else {
        dim3 grid((N + 255) / 256, M);
        qat_gemm_naive<<<grid, 256, 0, stream>>>(x, w, b, out, M, N, K);
    }
}